// Round 15
// baseline (355.635 us; speedup 1.0000x reference)
//
#include <hip/hip_runtime.h>

#define BT    8192
#define DIM   512
#define NLAT  10000
#define LPAD2 10240   // 80 * 128
#define NG    20
#define CV    5000

typedef short bf16x8 __attribute__((ext_vector_type(8)));
typedef float f32x4  __attribute__((ext_vector_type(4)));
typedef unsigned short u16;
typedef u16 u16x8 __attribute__((ext_vector_type(8)));
typedef u16 u16x4 __attribute__((ext_vector_type(4)));

static __device__ __forceinline__ u16 f2bf(float f) {
    union { float f; unsigned u; } v; v.f = f;
    unsigned r = v.u + 0x7FFF + ((v.u >> 16) & 1);   // RNE
    return (u16)(r >> 16);
}
static __device__ __forceinline__ float bf2f(u16 b) {
    union { unsigned u; float f; } v; v.u = ((unsigned)b) << 16; return v.f;
}

static __device__ __forceinline__ void gload16(const void* g, void* l) {
    __builtin_amdgcn_global_load_lds(
        (const __attribute__((address_space(1))) unsigned int*)g,
        (__attribute__((address_space(3))) unsigned int*)l,
        16, 0, 0);
}

// ---------------- char_table f32 -> bf16 copy -----------------
__global__ __launch_bounds__(256) void ct2bf_kernel(
        const float* __restrict__ ct, u16* __restrict__ ctb) {
    const long base = ((long)blockIdx.x * 256 + threadIdx.x) * 8;
    float4 a = *(const float4*)(ct + base);
    float4 b = *(const float4*)(ct + base + 4);
    u16x8 v = { f2bf(a.x), f2bf(a.y), f2bf(a.z), f2bf(a.w),
                f2bf(b.x), f2bf(b.y), f2bf(b.z), f2bf(b.w) };
    *(u16x8*)(ctb + base) = v;
}

// ---------------- lang_emb: 2 tokens per wave --------------
__global__ __launch_bounds__(256) void lang_kernel(
        const int* __restrict__ x, const u16* __restrict__ ctb,
        float* __restrict__ lang, u16* __restrict__ qb) {
    const int wv  = threadIdx.x >> 6;
    const int tl  = threadIdx.x & 63;
    const int tok0 = blockIdx.x * 8 + wv * 2;
    const int* xr0 = x + tok0 * NG;
    const int* xr1 = xr0 + NG;
    float s0[8], s1[8];
    #pragma unroll
    for (int i = 0; i < 8; ++i) { s0[i] = 0.f; s1[i] = 0.f; }
    #pragma unroll
    for (int j = 0; j < NG; ++j) {
        int c0 = xr0[j], c1 = xr1[j];
        if (c0 != 1) {
            u16x8 v = *(const u16x8*)(ctb + (long)c0 * DIM + tl * 8);
            #pragma unroll
            for (int i = 0; i < 8; ++i) s0[i] += bf2f(v[i]);
        }
        if (c1 != 1) {
            u16x8 v = *(const u16x8*)(ctb + (long)c1 * DIM + tl * 8);
            #pragma unroll
            for (int i = 0; i < 8; ++i) s1[i] += bf2f(v[i]);
        }
    }
    #pragma unroll
    for (int p = 0; p < 2; ++p) {
        float* s = p ? s1 : s0;
        const long tok = tok0 + p;
        float4 lo, hi;
        lo.x = tanhf(s[0]); lo.y = tanhf(s[1]); lo.z = tanhf(s[2]); lo.w = tanhf(s[3]);
        hi.x = tanhf(s[4]); hi.y = tanhf(s[5]); hi.z = tanhf(s[6]); hi.w = tanhf(s[7]);
        *(float4*)(lang + tok * DIM + tl * 8)     = lo;
        *(float4*)(lang + tok * DIM + tl * 8 + 4) = hi;
        u16x8 o = { f2bf(lo.x), f2bf(lo.y), f2bf(lo.z), f2bf(lo.w),
                    f2bf(hi.x), f2bf(hi.y), f2bf(hi.z), f2bf(hi.w) };
        *(u16x8*)(qb + tok * DIM + tl * 8) = o;
    }
}

// -------- latent_mat f32 -> kvg bf16 [LPAD2][DIM] and latT bf16 [DIM][LPAD2] --------
__global__ __launch_bounds__(256) void conv_kernel(
        const float* __restrict__ lm, u16* __restrict__ kvg, u16* __restrict__ latT) {
    __shared__ u16 tile[64][514];
    const int lb = blockIdx.x * 64;
    const int t  = threadIdx.x;

    #pragma unroll 4
    for (int i = 0; i < 16; ++i) {
        int ch  = t + i * 256;
        int r   = ch >> 6;
        int c8  = ch & 63;
        int row = lb + r;
        u16x8 v = {0,0,0,0,0,0,0,0};
        if (row < NLAT) {
            const float* src = lm + (long)row * DIM + c8 * 8;
            float4 a = *(const float4*)src;
            float4 b = *(const float4*)(src + 4);
            v[0]=f2bf(a.x); v[1]=f2bf(a.y); v[2]=f2bf(a.z); v[3]=f2bf(a.w);
            v[4]=f2bf(b.x); v[5]=f2bf(b.y); v[6]=f2bf(b.z); v[7]=f2bf(b.w);
        }
        *(u16x8*)(kvg + (long)row * DIM + c8 * 8) = v;
        #pragma unroll
        for (int j = 0; j < 8; ++j) tile[r][c8 * 8 + j] = v[j];
    }
    __syncthreads();
    #pragma unroll 4
    for (int i = 0; i < 16; ++i) {
        int ch = t + i * 256;
        int d  = ch >> 3;
        int c8 = ch & 7;
        u16x8 v;
        #pragma unroll
        for (int j = 0; j < 8; ++j) v[j] = tile[c8 * 8 + j][d];
        *(u16x8*)(latT + (long)d * LPAD2 + lb + c8 * 8) = v;
    }
}

// ======================= GEMM1 (R14-proven): 256x128 BK=32 depth-3 ==================
#define G1_COMPUTE(buf) {                                                      \
    bf16x8 af_[4], bf_[4];                                                     \
    _Pragma("unroll")                                                          \
    for (int mf_ = 0; mf_ < 4; ++mf_) {                                        \
        const int rA_ = wm * 64 + mf_ * 16 + lr;                               \
        const int ck_ = g ^ ((rA_ >> 1) & 3);                                  \
        af_[mf_] = *(const bf16x8*)&lds[buf][rA_ * 32 + ck_ * 8];              \
    }                                                                          \
    _Pragma("unroll")                                                          \
    for (int nf_ = 0; nf_ < 4; ++nf_) {                                        \
        const int rB_ = wn * 64 + nf_ * 16 + lr;                               \
        const int ck_ = g ^ ((rB_ >> 1) & 3);                                  \
        bf_[nf_] = *(const bf16x8*)&lds[buf][8192 + rB_ * 32 + ck_ * 8];       \
    }                                                                          \
    __builtin_amdgcn_s_setprio(1);                                             \
    _Pragma("unroll")                                                          \
    for (int mf_ = 0; mf_ < 4; ++mf_)                                          \
        _Pragma("unroll")                                                      \
        for (int nf_ = 0; nf_ < 4; ++nf_)                                      \
            acc[mf_][nf_] = __builtin_amdgcn_mfma_f32_16x16x32_bf16(           \
                af_[mf_], bf_[nf_], acc[mf_][nf_], 0, 0, 0);                   \
    __builtin_amdgcn_s_setprio(0);                                             \
}

#define G1_STAGE(buf, kt) {                                                    \
    const int k0_ = (kt) * 32;                                                 \
    {                                                                          \
        int ch_ = t;                                                           \
        int row_ = ch_ >> 2, c2_ = ch_ & 3;                                    \
        int sc_ = (c2_ ^ ((row_ >> 1) & 3)) * 8;                               \
        gload16(Q + (m0 + row_) * (long)DIM + k0_ + sc_, &lds[buf][ch_ * 8]);  \
        ch_ = t + 512; row_ = ch_ >> 2; c2_ = ch_ & 3;                         \
        sc_ = (c2_ ^ ((row_ >> 1) & 3)) * 8;                                   \
        gload16(Q + (m0 + row_) * (long)DIM + k0_ + sc_, &lds[buf][ch_ * 8]);  \
        row_ = t >> 2; c2_ = t & 3;                                            \
        sc_ = (c2_ ^ ((row_ >> 1) & 3)) * 8;                                   \
        gload16(Bgp + (long)row_ * DIM + k0_ + sc_, &lds[buf][8192 + t * 8]);  \
    }                                                                          \
}

#define G1_STEP(kt, vmn) {                                                     \
    asm volatile("s_waitcnt vmcnt(" #vmn ")" ::: "memory");                    \
    __builtin_amdgcn_s_barrier();                                              \
    G1_COMPUTE((kt) % 3);                                                      \
    __builtin_amdgcn_s_barrier();                                              \
}

__global__ __launch_bounds__(512, 4) void gemm1_kernel(
        const u16* __restrict__ Q, const u16* __restrict__ L,
        u16* __restrict__ P, float* __restrict__ rowsum,
        int n0_global, int npanels, int pstride) {
    __shared__ u16 lds[3][12288];           // 72 KB -> 2 blocks/CU

    const int nwg = 32 * npanels;
    const int cpx = nwg >> 3;
    const int bid = blockIdx.x;
    const int wg  = (bid & 7) * cpx + (bid >> 3);
    int mb, nb;
    if (npanels == 80) {
        const int st = wg / 80, lt = wg % 80;
        const int lmb = lt & 7, lnb = lt >> 3;
        const int smb = st & 3, snb = st >> 2;
        mb = smb * 8 + lmb;
        nb = snb * 10 + lnb;
    } else {
        mb = wg & 31;
        nb = wg >> 5;
    }
    const long m0    = (long)mb * 256;
    const int  ncol0 = n0_global + nb * 128;

    const u16* Bgp = L + (long)ncol0 * DIM;

    const int t = threadIdx.x, lane = t & 63, w = t >> 6;
    const int wm = w >> 1, wn = w & 1;
    const int g = lane >> 4, lr = lane & 15;

    f32x4 acc[4][4];
    #pragma unroll
    for (int m = 0; m < 4; ++m)
        #pragma unroll
        for (int n = 0; n < 4; ++n) acc[m][n] = f32x4{0.f,0.f,0.f,0.f};

    G1_STAGE(0, 0);
    G1_STAGE(1, 1);
    G1_STAGE(2, 2);

    #pragma unroll 1
    for (int kt = 0; kt < 13; ++kt) {
        asm volatile("s_waitcnt vmcnt(6)" ::: "memory");
        __builtin_amdgcn_s_barrier();
        G1_COMPUTE(kt % 3);
        __builtin_amdgcn_s_barrier();
        G1_STAGE(kt % 3, kt + 3);
    }
    G1_STEP(13, 6);
    G1_STEP(14, 3);
    asm volatile("s_waitcnt vmcnt(0)" ::: "memory");
    __builtin_amdgcn_s_barrier();
    G1_COMPUTE(15 % 3);
    __syncthreads();

    // ---- epilogue: exp + mask; pack bf16 P-tile into lds (swizzled) ----
    u16* lds16 = &lds[0][0];
    #pragma unroll
    for (int mf = 0; mf < 4; ++mf)
        #pragma unroll
        for (int nf = 0; nf < 4; ++nf) {
            const int col = ncol0 + wn * 64 + nf * 16 + lr;
            const bool ok = (col < NLAT);
            const int lcol = wn * 64 + nf * 16 + lr;
            #pragma unroll
            for (int r = 0; r < 4; ++r) {
                float p = ok ? __expf(acc[mf][nf][r]) : 0.f;
                acc[mf][nf][r] = p;
                const int row = wm * 64 + mf * 16 + g * 4 + r;
                lds16[row * 128 + (lcol ^ ((row & 15) << 3))] = f2bf(p);
            }
        }

    // ---- rowsum partials ----
    #pragma unroll
    for (int mf = 0; mf < 4; ++mf) {
        float sv[4] = {0.f, 0.f, 0.f, 0.f};
        #pragma unroll
        for (int nf = 0; nf < 4; ++nf)
            #pragma unroll
            for (int r = 0; r < 4; ++r) sv[r] += acc[mf][nf][r];
        #pragma unroll
        for (int r = 0; r < 4; ++r) {
            float s = sv[r];
            s += __shfl_xor(s, 1); s += __shfl_xor(s, 2);
            s += __shfl_xor(s, 4); s += __shfl_xor(s, 8);
            if (lr == 0)
                atomicAdd(&rowsum[m0 + wm * 64 + mf * 16 + g * 4 + r], s);
        }
    }

    // ---- P store: full-line u16x8 stores ----
    __syncthreads();
    const int pbase = ncol0 - n0_global;
    #pragma unroll
    for (int it = 0; it < 8; ++it) {
        const int flat = t + it * 512;
        const int row = flat >> 4, ck = flat & 15;
        u16x8 v = *(const u16x8*)&lds16[row * 128 + ((ck ^ (row & 15)) * 8)];
        *(u16x8*)(P + (m0 + row) * (long)pstride + pbase + ck * 8) = v;
    }
}

// ========== GEMM2: 4-phase quadrant schedule, 256x256 BK=64, 128KB LDS ==============
// 8 waves as 2x4 over each 128x128 C-quadrant. dbuf[2] x halves {A0,A1,B0,B1}
// (each 128x64). Stage ring: p0->(kt+1).A1, p1->(kt+1).B1, p2->(kt+2).B0,
// p3->(kt+2).A0. Every read's stage is >=5 phases old; vmcnt(6) at phase top
// forces >=4-back landed (=> >=5-back for next phase's reads). Slot overwrites
// are barrier-separated from last reads (B0 read p0/p1, staged p2; A0 read
// p0/p2, staged p3; A1/B1 read thru p3, staged next-kt p0/p1 in other dbuf).
#define SLOT(d, h) ((d) * 32768 + (h) * 8192)

#define G2_STAGE_H(kt2, h) {                                                   \
    const int d2_ = (kt2) & 1;                                                 \
    const int kc_ = (step_off + (kt2)) * 64;                                   \
    _Pragma("unroll")                                                          \
    for (int i_ = 0; i_ < 2; ++i_) {                                           \
        int ch_ = t + i_ * 512;                                                \
        int row_ = ch_ >> 3;                                                   \
        int sc_ = ((ch_ & 7) ^ (row_ & 7)) * 8;                                \
        if ((h) < 2) {                                                         \
            gload16(P + (m0 + (h) * 128 + row_) * (long)pstride + kc_ + sc_,   \
                    &lds[SLOT(d2_, (h)) + ch_ * 8]);                           \
        } else {                                                               \
            gload16(LT + (long)(nbase + ((h) - 2) * 128 + row_) * LPAD2        \
                        + n0_global + kc_ + sc_,                               \
                    &lds[SLOT(d2_, (h)) + ch_ * 8]);                           \
        }                                                                      \
    }                                                                          \
}

#define G2_PHASE(kt_, mh_, nh_, skt_, sh_) {                                   \
    const int d_ = (kt_) & 1;                                                  \
    bf16x8 af_[4][2], bf_[2][2];                                               \
    _Pragma("unroll")                                                          \
    for (int mf_ = 0; mf_ < 4; ++mf_) {                                        \
        const int ra_ = qr * 64 + mf_ * 16 + lr;                               \
        _Pragma("unroll")                                                      \
        for (int kk_ = 0; kk_ < 2; ++kk_)                                      \
            af_[mf_][kk_] = *(const bf16x8*)&lds[SLOT(d_, (mh_)) + ra_ * 64    \
                + (((kk_ * 4 + g) ^ (lr & 7)) * 8)];                           \
    }                                                                          \
    _Pragma("unroll")                                                          \
    for (int nf_ = 0; nf_ < 2; ++nf_) {                                        \
        const int rb_ = qc * 32 + nf_ * 16 + lr;                               \
        _Pragma("unroll")                                                      \
        for (int kk_ = 0; kk_ < 2; ++kk_)                                      \
            bf_[nf_][kk_] = *(const bf16x8*)&lds[SLOT(d_, 2 + (nh_)) + rb_ * 64 \
                + (((kk_ * 4 + g) ^ (lr & 7)) * 8)];                           \
    }                                                                          \
    if ((skt_) >= 2 && (skt_) < NT) G2_STAGE_H((skt_), (sh_));                 \
    if ((kt_) >= 2 && (kt_) < NT - 2) {                                        \
        asm volatile("s_waitcnt vmcnt(6)" ::: "memory");                       \
    } else {                                                                   \
        asm volatile("s_waitcnt vmcnt(0)" ::: "memory");                       \
    }                                                                          \
    __builtin_amdgcn_s_barrier();                                              \
    __builtin_amdgcn_s_setprio(1);                                             \
    _Pragma("unroll")                                                          \
    for (int mf_ = 0; mf_ < 4; ++mf_)                                          \
        _Pragma("unroll")                                                      \
        for (int nf_ = 0; nf_ < 2; ++nf_)                                      \
            _Pragma("unroll")                                                  \
            for (int kk_ = 0; kk_ < 2; ++kk_)                                  \
                acc[mh_][nh_][mf_][nf_] = __builtin_amdgcn_mfma_f32_16x16x32_bf16( \
                    af_[mf_][kk_], bf_[nf_][kk_], acc[mh_][nh_][mf_][nf_], 0, 0, 0); \
    __builtin_amdgcn_s_setprio(0);                                             \
    __builtin_amdgcn_s_barrier();                                              \
}

__global__ __launch_bounds__(512, 2) void gemm2_kernel(
        const u16* __restrict__ P, const u16* __restrict__ LT,
        float* __restrict__ out, float* __restrict__ parts,
        int pstride, int kcols, int n0_global, int splitk, int accum) {
    __shared__ u16 lds[65536];              // 128 KB -> 1 block/CU

    const int per = 2 * splitk;             // (nb, s) inner
    const int nwg = 32 * per;
    const int cpx = nwg >> 3;
    const int bid = blockIdx.x;
    const int wg  = (bid & 7) * cpx + (bid >> 3);
    const int mb  = wg / per;               // OUTER: M-block (32)
    const int inr = wg % per;
    const int nb  = inr / splitk;           // 0..1 (BN=256)
    const int s   = inr % splitk;

    const long m0    = (long)mb * 256;
    const int  nbase = nb * 256;

    const int nsteps = kcols / 64;          // K-tiles of 64
    const int q = nsteps / splitk, rr = nsteps % splitk;
    const int NT       = q + (s < rr ? 1 : 0);
    const int step_off = s * q + (s < rr ? s : rr);

    const int t = threadIdx.x, lane = t & 63, w = t >> 6;
    const int qr = w >> 2, qc = w & 3;      // 2x4 waves over a 128x128 quadrant
    const int g = lane >> 4, lr = lane & 15;

    float* buf = (s == 0) ? out : (parts + (long)(s - 1) * BT * DIM);

    f32x4 acc[2][2][4][2];
    #pragma unroll
    for (int a = 0; a < 2; ++a)
        #pragma unroll
        for (int b = 0; b < 2; ++b)
            #pragma unroll
            for (int m = 0; m < 4; ++m)
                #pragma unroll
                for (int n = 0; n < 2; ++n)
                    acc[a][b][m][n] = f32x4{0.f,0.f,0.f,0.f};

    // prologue: stage K-tiles 0 and 1 fully
    G2_STAGE_H(0, 0); G2_STAGE_H(0, 1); G2_STAGE_H(0, 2); G2_STAGE_H(0, 3);
    if (NT > 1) { G2_STAGE_H(1, 0); G2_STAGE_H(1, 1); G2_STAGE_H(1, 2); G2_STAGE_H(1, 3); }
    asm volatile("s_waitcnt vmcnt(0)" ::: "memory");
    __builtin_amdgcn_s_barrier();

    #pragma unroll 1
    for (int kt = 0; kt < NT; ++kt) {
        G2_PHASE(kt, 0, 0, kt + 1, 1);      // quadrant (0,0); stage (kt+1).A1
        G2_PHASE(kt, 1, 0, kt + 1, 3);      // quadrant (1,0); stage (kt+1).B1
        G2_PHASE(kt, 0, 1, kt + 2, 2);      // quadrant (0,1); stage (kt+2).B0
        G2_PHASE(kt, 1, 1, kt + 2, 0);      // quadrant (1,1); stage (kt+2).A0
    }

    // ---- epilogue ----
    #pragma unroll
    for (int mh = 0; mh < 2; ++mh)
        #pragma unroll
        for (int nh = 0; nh < 2; ++nh)
            #pragma unroll
            for (int mf = 0; mf < 4; ++mf)
                #pragma unroll
                for (int nf = 0; nf < 2; ++nf) {
                    const int col = nbase + nh * 128 + qc * 32 + nf * 16 + lr;
                    #pragma unroll
                    for (int r = 0; r < 4; ++r) {
                        const long row = m0 + mh * 128 + qr * 64 + mf * 16 + g * 4 + r;
                        float v = acc[mh][nh][mf][nf][r];
                        if (accum) v += buf[row * DIM + col];
                        buf[row * DIM + col] = v;
                    }
                }
}

// -------- final: out = (out + sum parts)/rowsum + lang; first-token override --------
__global__ __launch_bounds__(256) void final_kernel(
        float* __restrict__ out, const float* __restrict__ parts,
        const float* __restrict__ lang, const float* __restrict__ rowsum,
        const int* __restrict__ x, const float* __restrict__ ct, int nparts) {
    const int tok   = blockIdx.x * 2 + (threadIdx.x >> 7);
    const int c4    = (threadIdx.x & 127) * 4;
    const long idx  = (long)tok * DIM + c4;
    const float inv = 1.f / rowsum[tok];
    const int first = x[tok * NG];

    float4 v = *(const float4*)(out + idx);
    for (int p = 1; p < nparts; ++p) {
        float4 pv = *(const float4*)(parts + (long)(p - 1) * BT * DIM + idx);
        v.x += pv.x; v.y += pv.y; v.z += pv.z; v.w += pv.w;
    }
    float4 lg = *(const float4*)(lang + idx);
    v.x = v.x * inv + lg.x; v.y = v.y * inv + lg.y;
    v.z = v.z * inv + lg.z; v.w = v.w * inv + lg.w;
    if (first < 4) v = *(const float4*)(ct + first * DIM + c4);
    *(float4*)(out + idx) = v;
}

extern "C" void kernel_launch(void* const* d_in, const int* in_sizes, int n_in,
                              void* d_out, int out_size, void* d_ws, size_t ws_size,
                              hipStream_t stream) {
    const int*   x  = (const int*)d_in[0];
    const float* ct = (const float*)d_in[1];
    const float* lm = (const float*)d_in[2];
    float* out = (float*)d_out;

    char* ws = (char*)d_ws;
    size_t off = 0;
    u16*   qb   = (u16*)(ws + off);   off += (size_t)BT * DIM * 2;      // 8 MB
    float* lang = (float*)(ws + off); off += (size_t)BT * DIM * 4;      // 16 MB
    u16*   kvg  = (u16*)(ws + off);   off += (size_t)LPAD2 * DIM * 2;   // 10 MB
    u16*   latT = (u16*)(ws + off);   off += (size_t)DIM * LPAD2 * 2;   // 10 MB
    u16*   ctb  = (u16*)(ws + off);   off += (size_t)CV * DIM * 2;      // 5.12 MB
    float* rowsum = (float*)(ws + off); off += (size_t)BT * 4;          // 32 KB
    u16*   P    = (u16*)(ws + off);
    const size_t fixed = off;

    const int panels_total = LPAD2 / 128;                  // 80
    const size_t pfull = (size_t)BT * LPAD2 * 2;           // 160 MiB
    const size_t partb = (size_t)BT * DIM * 4;             // 16 MiB

    int splitk = 1, ppc = panels_total;
    float* parts = out;   // dummy when unused
    if (ws_size >= fixed + pfull + 3 * partb) {
        splitk = 4;
        parts = (float*)(ws + fixed + pfull);
    } else if (ws_size >= fixed + pfull + partb) {
        splitk = 2;
        parts = (float*)(ws + fixed + pfull);
    } else if (ws_size >= fixed + pfull) {
        splitk = 1;
    } else {
        size_t avail = (ws_size > fixed) ? (ws_size - fixed) : 0;
        size_t p = avail / ((size_t)BT * 128 * 2);
        ppc = (int)(p < 1 ? 1 : (p > (size_t)panels_total ? (size_t)panels_total : p));
        if (ppc & 1) ppc = (ppc > 1) ? ppc - 1 : 1;
    }
    const int pstride = ppc * 128;

    hipMemsetAsync(rowsum, 0, (size_t)BT * 4, stream);
    ct2bf_kernel<<<CV * DIM / (256 * 8), 256, 0, stream>>>(ct, ctb);
    lang_kernel<<<BT / 8, 256, 0, stream>>>(x, ctb, lang, qb);
    conv_kernel<<<LPAD2 / 64, 256, 0, stream>>>(lm, kvg, latT);

    int chunk = 0;
    for (int cs = 0; cs < panels_total; cs += ppc, ++chunk) {
        const int np = (panels_total - cs < ppc) ? (panels_total - cs) : ppc;
        gemm1_kernel<<<32 * np, 512, 0, stream>>>(qb, kvg, P, rowsum,
                                                  cs * 128, np, pstride);
        gemm2_kernel<<<32 * 2 * splitk, 512, 0, stream>>>(P, latT, out, parts,
                                                          pstride, np * 128, cs * 128,
                                                          splitk, chunk > 0 ? 1 : 0);
    }
    final_kernel<<<BT / 2, 256, 0, stream>>>(out, parts, lang, rowsum, x, ct, splitk);
}

// Round 16
// 270.173 us; speedup vs baseline: 1.3163x; 1.3163x over previous
//
#include <hip/hip_runtime.h>

#define BT    8192
#define DIM   512
#define NLAT  10000
#define LPAD2 10240   // 80 * 128
#define NG    20
#define CV    5000

typedef short bf16x8 __attribute__((ext_vector_type(8)));
typedef float f32x4  __attribute__((ext_vector_type(4)));
typedef unsigned short u16;
typedef u16 u16x8 __attribute__((ext_vector_type(8)));
typedef u16 u16x4 __attribute__((ext_vector_type(4)));

static __device__ __forceinline__ u16 f2bf(float f) {
    union { float f; unsigned u; } v; v.f = f;
    unsigned r = v.u + 0x7FFF + ((v.u >> 16) & 1);   // RNE
    return (u16)(r >> 16);
}
static __device__ __forceinline__ float bf2f(u16 b) {
    union { unsigned u; float f; } v; v.u = ((unsigned)b) << 16; return v.f;
}

static __device__ __forceinline__ void gload16(const void* g, void* l) {
    __builtin_amdgcn_global_load_lds(
        (const __attribute__((address_space(1))) unsigned int*)g,
        (__attribute__((address_space(3))) unsigned int*)l,
        16, 0, 0);
}

// ---------------- char_table f32 -> bf16 copy -----------------
__global__ __launch_bounds__(256) void ct2bf_kernel(
        const float* __restrict__ ct, u16* __restrict__ ctb) {
    const long base = ((long)blockIdx.x * 256 + threadIdx.x) * 8;
    float4 a = *(const float4*)(ct + base);
    float4 b = *(const float4*)(ct + base + 4);
    u16x8 v = { f2bf(a.x), f2bf(a.y), f2bf(a.z), f2bf(a.w),
                f2bf(b.x), f2bf(b.y), f2bf(b.z), f2bf(b.w) };
    *(u16x8*)(ctb + base) = v;
}

// ---------------- lang_emb: 2 tokens per wave --------------
__global__ __launch_bounds__(256) void lang_kernel(
        const int* __restrict__ x, const u16* __restrict__ ctb,
        float* __restrict__ lang, u16* __restrict__ qb) {
    const int wv  = threadIdx.x >> 6;
    const int tl  = threadIdx.x & 63;
    const int tok0 = blockIdx.x * 8 + wv * 2;
    const int* xr0 = x + tok0 * NG;
    const int* xr1 = xr0 + NG;
    float s0[8], s1[8];
    #pragma unroll
    for (int i = 0; i < 8; ++i) { s0[i] = 0.f; s1[i] = 0.f; }
    #pragma unroll
    for (int j = 0; j < NG; ++j) {
        int c0 = xr0[j], c1 = xr1[j];
        if (c0 != 1) {
            u16x8 v = *(const u16x8*)(ctb + (long)c0 * DIM + tl * 8);
            #pragma unroll
            for (int i = 0; i < 8; ++i) s0[i] += bf2f(v[i]);
        }
        if (c1 != 1) {
            u16x8 v = *(const u16x8*)(ctb + (long)c1 * DIM + tl * 8);
            #pragma unroll
            for (int i = 0; i < 8; ++i) s1[i] += bf2f(v[i]);
        }
    }
    #pragma unroll
    for (int p = 0; p < 2; ++p) {
        float* s = p ? s1 : s0;
        const long tok = tok0 + p;
        float4 lo, hi;
        lo.x = tanhf(s[0]); lo.y = tanhf(s[1]); lo.z = tanhf(s[2]); lo.w = tanhf(s[3]);
        hi.x = tanhf(s[4]); hi.y = tanhf(s[5]); hi.z = tanhf(s[6]); hi.w = tanhf(s[7]);
        *(float4*)(lang + tok * DIM + tl * 8)     = lo;
        *(float4*)(lang + tok * DIM + tl * 8 + 4) = hi;
        u16x8 o = { f2bf(lo.x), f2bf(lo.y), f2bf(lo.z), f2bf(lo.w),
                    f2bf(hi.x), f2bf(hi.y), f2bf(hi.z), f2bf(hi.w) };
        *(u16x8*)(qb + tok * DIM + tl * 8) = o;
    }
}

// -------- latent_mat f32 -> kvg bf16 [LPAD2][DIM] and latT bf16 [DIM][LPAD2] --------
__global__ __launch_bounds__(256) void conv_kernel(
        const float* __restrict__ lm, u16* __restrict__ kvg, u16* __restrict__ latT) {
    __shared__ u16 tile[64][514];
    const int lb = blockIdx.x * 64;
    const int t  = threadIdx.x;

    #pragma unroll 4
    for (int i = 0; i < 16; ++i) {
        int ch  = t + i * 256;
        int r   = ch >> 6;
        int c8  = ch & 63;
        int row = lb + r;
        u16x8 v = {0,0,0,0,0,0,0,0};
        if (row < NLAT) {
            const float* src = lm + (long)row * DIM + c8 * 8;
            float4 a = *(const float4*)src;
            float4 b = *(const float4*)(src + 4);
            v[0]=f2bf(a.x); v[1]=f2bf(a.y); v[2]=f2bf(a.z); v[3]=f2bf(a.w);
            v[4]=f2bf(b.x); v[5]=f2bf(b.y); v[6]=f2bf(b.z); v[7]=f2bf(b.w);
        }
        *(u16x8*)(kvg + (long)row * DIM + c8 * 8) = v;
        #pragma unroll
        for (int j = 0; j < 8; ++j) tile[r][c8 * 8 + j] = v[j];
    }
    __syncthreads();
    #pragma unroll 4
    for (int i = 0; i < 16; ++i) {
        int ch = t + i * 256;
        int d  = ch >> 3;
        int c8 = ch & 7;
        u16x8 v;
        #pragma unroll
        for (int j = 0; j < 8; ++j) v[j] = tile[c8 * 8 + j][d];
        *(u16x8*)(latT + (long)d * LPAD2 + lb + c8 * 8) = v;
    }
}

// ======================= shared 256x128 BK=32 depth-3 machinery =====================
// lds buf: A 256x32 (8192 elems) | B 128x32 (4096 elems) = 24 KB; 3 bufs = 72 KB.
#define G1_COMPUTE(buf) {                                                      \
    bf16x8 af_[4], bf_[4];                                                     \
    _Pragma("unroll")                                                          \
    for (int mf_ = 0; mf_ < 4; ++mf_) {                                        \
        const int rA_ = wm * 64 + mf_ * 16 + lr;                               \
        const int ck_ = g ^ ((rA_ >> 1) & 3);                                  \
        af_[mf_] = *(const bf16x8*)&lds[buf][rA_ * 32 + ck_ * 8];              \
    }                                                                          \
    _Pragma("unroll")                                                          \
    for (int nf_ = 0; nf_ < 4; ++nf_) {                                        \
        const int rB_ = wn * 64 + nf_ * 16 + lr;                               \
        const int ck_ = g ^ ((rB_ >> 1) & 3);                                  \
        bf_[nf_] = *(const bf16x8*)&lds[buf][8192 + rB_ * 32 + ck_ * 8];       \
    }                                                                          \
    __builtin_amdgcn_s_setprio(1);                                             \
    _Pragma("unroll")                                                          \
    for (int mf_ = 0; mf_ < 4; ++mf_)                                          \
        _Pragma("unroll")                                                      \
        for (int nf_ = 0; nf_ < 4; ++nf_)                                      \
            acc[mf_][nf_] = __builtin_amdgcn_mfma_f32_16x16x32_bf16(           \
                af_[mf_], bf_[nf_], acc[mf_][nf_], 0, 0, 0);                   \
    __builtin_amdgcn_s_setprio(0);                                             \
}

// ======================= GEMM1: P = exp(Q @ kvg^T), K=512 ===========================
#define G1_STAGE(buf, kt) {                                                    \
    const int k0_ = (kt) * 32;                                                 \
    {                                                                          \
        int ch_ = t;                                                           \
        int row_ = ch_ >> 2, c2_ = ch_ & 3;                                    \
        int sc_ = (c2_ ^ ((row_ >> 1) & 3)) * 8;                               \
        gload16(Q + (m0 + row_) * (long)DIM + k0_ + sc_, &lds[buf][ch_ * 8]);  \
        ch_ = t + 512; row_ = ch_ >> 2; c2_ = ch_ & 3;                         \
        sc_ = (c2_ ^ ((row_ >> 1) & 3)) * 8;                                   \
        gload16(Q + (m0 + row_) * (long)DIM + k0_ + sc_, &lds[buf][ch_ * 8]);  \
        row_ = t >> 2; c2_ = t & 3;                                            \
        sc_ = (c2_ ^ ((row_ >> 1) & 3)) * 8;                                   \
        gload16(Bgp + (long)row_ * DIM + k0_ + sc_, &lds[buf][8192 + t * 8]);  \
    }                                                                          \
}

#define G1_STEP(kt, vmn) {                                                     \
    asm volatile("s_waitcnt vmcnt(" #vmn ")" ::: "memory");                    \
    __builtin_amdgcn_s_barrier();                                              \
    G1_COMPUTE((kt) % 3);                                                      \
    __builtin_amdgcn_s_barrier();                                              \
}

__global__ __launch_bounds__(512, 4) void gemm1_kernel(
        const u16* __restrict__ Q, const u16* __restrict__ L,
        u16* __restrict__ P, float* __restrict__ rowsum,
        int n0_global, int npanels, int pstride) {
    __shared__ u16 lds[3][12288];           // 72 KB -> 2 blocks/CU

    const int nwg = 32 * npanels;
    const int cpx = nwg >> 3;
    const int bid = blockIdx.x;
    const int wg  = (bid & 7) * cpx + (bid >> 3);
    int mb, nb;
    if (npanels == 80) {
        // 2-D supertiles: 8 mb x 10 nb (working set ~3.25 MB < 4 MB L2/XCD)
        const int st = wg / 80, lt = wg % 80;
        const int lmb = lt & 7, lnb = lt >> 3;
        const int smb = st & 3, snb = st >> 2;
        mb = smb * 8 + lmb;
        nb = snb * 10 + lnb;
    } else {
        mb = wg & 31;
        nb = wg >> 5;
    }
    const long m0    = (long)mb * 256;
    const int  ncol0 = n0_global + nb * 128;

    const u16* Bgp = L + (long)ncol0 * DIM;

    const int t = threadIdx.x, lane = t & 63, w = t >> 6;
    const int wm = w >> 1, wn = w & 1;       // 4M x 2N waves: 64x64 out each
    const int g = lane >> 4, lr = lane & 15;

    f32x4 acc[4][4];
    #pragma unroll
    for (int m = 0; m < 4; ++m)
        #pragma unroll
        for (int n = 0; n < 4; ++n) acc[m][n] = f32x4{0.f,0.f,0.f,0.f};

    G1_STAGE(0, 0);
    G1_STAGE(1, 1);
    G1_STAGE(2, 2);

    #pragma unroll 1
    for (int kt = 0; kt < 13; ++kt) {                  // 16 K-tiles total
        asm volatile("s_waitcnt vmcnt(6)" ::: "memory");
        __builtin_amdgcn_s_barrier();
        G1_COMPUTE(kt % 3);
        __builtin_amdgcn_s_barrier();
        G1_STAGE(kt % 3, kt + 3);
    }
    G1_STEP(13, 6);
    G1_STEP(14, 3);
    asm volatile("s_waitcnt vmcnt(0)" ::: "memory");
    __builtin_amdgcn_s_barrier();
    G1_COMPUTE(15 % 3);
    __syncthreads();                                   // lds now dead -> reuse for P

    // ---- epilogue: exp + mask; pack bf16 P-tile into lds (swizzled) ----
    u16* lds16 = &lds[0][0];
    #pragma unroll
    for (int mf = 0; mf < 4; ++mf)
        #pragma unroll
        for (int nf = 0; nf < 4; ++nf) {
            const int col = ncol0 + wn * 64 + nf * 16 + lr;
            const bool ok = (col < NLAT);
            const int lcol = wn * 64 + nf * 16 + lr;
            #pragma unroll
            for (int r = 0; r < 4; ++r) {
                float p = ok ? __expf(acc[mf][nf][r]) : 0.f;
                acc[mf][nf][r] = p;
                const int row = wm * 64 + mf * 16 + g * 4 + r;
                lds16[row * 128 + (lcol ^ ((row & 15) << 3))] = f2bf(p);
            }
        }

    // ---- rowsum partials ----
    #pragma unroll
    for (int mf = 0; mf < 4; ++mf) {
        float sv[4] = {0.f, 0.f, 0.f, 0.f};
        #pragma unroll
        for (int nf = 0; nf < 4; ++nf)
            #pragma unroll
            for (int r = 0; r < 4; ++r) sv[r] += acc[mf][nf][r];
        #pragma unroll
        for (int r = 0; r < 4; ++r) {
            float s = sv[r];
            s += __shfl_xor(s, 1); s += __shfl_xor(s, 2);
            s += __shfl_xor(s, 4); s += __shfl_xor(s, 8);
            if (lr == 0)
                atomicAdd(&rowsum[m0 + wm * 64 + mf * 16 + g * 4 + r], s);
        }
    }

    // ---- P store: full-line u16x8 stores ----
    __syncthreads();
    const int pbase = ncol0 - n0_global;
    #pragma unroll
    for (int it = 0; it < 8; ++it) {
        const int flat = t + it * 512;
        const int row = flat >> 4, ck = flat & 15;
        u16x8 v = *(const u16x8*)&lds16[row * 128 + ((ck ^ (row & 15)) * 8)];
        *(u16x8*)(P + (m0 + row) * (long)pstride + pbase + ck * 8) = v;
    }
}

// ============ GEMM2: buf = P @ latT^T, 256x128 BK=32 depth-3, split-K ===============
// mb OUTER / (nb,s) INNER: blocks sharing one mb's P rows co-reside on one XCD.
#define G2_STAGE(buf, kt) {                                                    \
    const int kloc_ = (step_off + (kt)) * 32;                                  \
    {                                                                          \
        int ch_ = t;                                                           \
        int row_ = ch_ >> 2, c2_ = ch_ & 3;                                    \
        int sc_ = (c2_ ^ ((row_ >> 1) & 3)) * 8;                               \
        gload16(P + (m0 + row_) * (long)pstride + kloc_ + sc_, &lds[buf][ch_ * 8]); \
        ch_ = t + 512; row_ = ch_ >> 2; c2_ = ch_ & 3;                         \
        sc_ = (c2_ ^ ((row_ >> 1) & 3)) * 8;                                   \
        gload16(P + (m0 + row_) * (long)pstride + kloc_ + sc_, &lds[buf][ch_ * 8]); \
        row_ = t >> 2; c2_ = t & 3;                                            \
        sc_ = (c2_ ^ ((row_ >> 1) & 3)) * 8;                                   \
        gload16(LT + (long)(nbase + row_) * LPAD2 + n0_global + kloc_ + sc_,   \
                &lds[buf][8192 + t * 8]);                                      \
    }                                                                          \
}

__global__ __launch_bounds__(512, 4) void gemm2_kernel(
        const u16* __restrict__ P, const u16* __restrict__ LT,
        float* __restrict__ out, float* __restrict__ parts,
        int pstride, int kcols, int n0_global, int splitk, int accum) {
    __shared__ u16 lds[3][12288];           // 72 KB

    const int per = 4 * splitk;
    const int nwg = 32 * per;
    const int cpx = nwg >> 3;
    const int bid = blockIdx.x;
    const int wg  = (bid & 7) * cpx + (bid >> 3);
    const int mb  = wg / per;                // OUTER: M-block (32)
    const int inr = wg % per;                // INNER: (nb, s)
    const int nb  = inr / splitk;
    const int s   = inr % splitk;

    const long m0    = (long)mb * 256;
    const int  nbase = nb * 128;

    const int nsteps = kcols / 32;
    const int q = nsteps / splitk, rr = nsteps % splitk;
    const int NT       = q + (s < rr ? 1 : 0);
    const int step_off = s * q + (s < rr ? s : rr);

    const int t = threadIdx.x, lane = t & 63, w = t >> 6;
    const int wm = w >> 1, wn = w & 1;
    const int g = lane >> 4, lr = lane & 15;

    float* buf = (s == 0) ? out : (parts + (long)(s - 1) * BT * DIM);

    f32x4 acc[4][4];
    #pragma unroll
    for (int m = 0; m < 4; ++m)
        #pragma unroll
        for (int n = 0; n < 4; ++n) acc[m][n] = f32x4{0.f,0.f,0.f,0.f};

    G2_STAGE(0, 0);
    G2_STAGE(1, 1);
    G2_STAGE(2, 2);

    #pragma unroll 1
    for (int kt = 0; kt < NT - 3; ++kt) {
        asm volatile("s_waitcnt vmcnt(6)" ::: "memory");
        __builtin_amdgcn_s_barrier();
        G1_COMPUTE(kt % 3);
        __builtin_amdgcn_s_barrier();
        G2_STAGE(kt % 3, kt + 3);
    }
    {
        asm volatile("s_waitcnt vmcnt(6)" ::: "memory");
        __builtin_amdgcn_s_barrier();
        G1_COMPUTE((NT - 3) % 3);
        __builtin_amdgcn_s_barrier();
    }
    {
        asm volatile("s_waitcnt vmcnt(3)" ::: "memory");
        __builtin_amdgcn_s_barrier();
        G1_COMPUTE((NT - 2) % 3);
        __builtin_amdgcn_s_barrier();
    }
    asm volatile("s_waitcnt vmcnt(0)" ::: "memory");
    __builtin_amdgcn_s_barrier();
    G1_COMPUTE((NT - 1) % 3);

    #pragma unroll
    for (int mf = 0; mf < 4; ++mf)
        #pragma unroll
        for (int nf = 0; nf < 4; ++nf) {
            const int col = nbase + wn * 64 + nf * 16 + lr;
            #pragma unroll
            for (int r = 0; r < 4; ++r) {
                const long row = m0 + wm * 64 + mf * 16 + g * 4 + r;
                float v = acc[mf][nf][r];
                if (accum) v += buf[row * DIM + col];
                buf[row * DIM + col] = v;
            }
        }
}

// -------- final: out = (out + sum parts)/rowsum + lang; first-token override --------
// Vectorized: one float4 per thread, 2 tokens per block.
__global__ __launch_bounds__(256) void final_kernel(
        float* __restrict__ out, const float* __restrict__ parts,
        const float* __restrict__ lang, const float* __restrict__ rowsum,
        const int* __restrict__ x, const float* __restrict__ ct, int nparts) {
    const int tok   = blockIdx.x * 2 + (threadIdx.x >> 7);
    const int c4    = (threadIdx.x & 127) * 4;
    const long idx  = (long)tok * DIM + c4;
    const float inv = 1.f / rowsum[tok];
    const int first = x[tok * NG];

    float4 v = *(const float4*)(out + idx);
    for (int p = 1; p < nparts; ++p) {
        float4 pv = *(const float4*)(parts + (long)(p - 1) * BT * DIM + idx);
        v.x += pv.x; v.y += pv.y; v.z += pv.z; v.w += pv.w;
    }
    float4 lg = *(const float4*)(lang + idx);
    v.x = v.x * inv + lg.x; v.y = v.y * inv + lg.y;
    v.z = v.z * inv + lg.z; v.w = v.w * inv + lg.w;
    if (first < 4) v = *(const float4*)(ct + first * DIM + c4);
    *(float4*)(out + idx) = v;
}

extern "C" void kernel_launch(void* const* d_in, const int* in_sizes, int n_in,
                              void* d_out, int out_size, void* d_ws, size_t ws_size,
                              hipStream_t stream) {
    const int*   x  = (const int*)d_in[0];
    const float* ct = (const float*)d_in[1];
    const float* lm = (const float*)d_in[2];
    float* out = (float*)d_out;

    char* ws = (char*)d_ws;
    size_t off = 0;
    u16*   qb   = (u16*)(ws + off);   off += (size_t)BT * DIM * 2;      // 8 MB
    float* lang = (float*)(ws + off); off += (size_t)BT * DIM * 4;      // 16 MB
    u16*   kvg  = (u16*)(ws + off);   off += (size_t)LPAD2 * DIM * 2;   // 10 MB
    u16*   latT = (u16*)(ws + off);   off += (size_t)DIM * LPAD2 * 2;   // 10 MB
    u16*   ctb  = (u16*)(ws + off);   off += (size_t)CV * DIM * 2;      // 5.12 MB
    float* rowsum = (float*)(ws + off); off += (size_t)BT * 4;          // 32 KB
    u16*   P    = (u16*)(ws + off);
    const size_t fixed = off;

    const int panels_total = LPAD2 / 128;                  // 80
    const size_t pfull = (size_t)BT * LPAD2 * 2;           // 160 MiB
    const size_t partb = (size_t)BT * DIM * 4;             // 16 MiB

    int splitk = 1, ppc = panels_total;
    float* parts = out;   // dummy when unused
    if (ws_size >= fixed + pfull + 3 * partb) {
        splitk = 4;
        parts = (float*)(ws + fixed + pfull);
    } else if (ws_size >= fixed + pfull + partb) {
        splitk = 2;
        parts = (float*)(ws + fixed + pfull);
    } else if (ws_size >= fixed + pfull) {
        splitk = 1;
    } else {
        size_t avail = (ws_size > fixed) ? (ws_size - fixed) : 0;
        size_t p = avail / ((size_t)BT * 128 * 2);
        ppc = (int)(p < 1 ? 1 : (p > (size_t)panels_total ? (size_t)panels_total : p));
        if (ppc & 1) ppc = (ppc > 1) ? ppc - 1 : 1;
    }
    const int pstride = ppc * 128;

    hipMemsetAsync(rowsum, 0, (size_t)BT * 4, stream);
    ct2bf_kernel<<<CV * DIM / (256 * 8), 256, 0, stream>>>(ct, ctb);
    lang_kernel<<<BT / 8, 256, 0, stream>>>(x, ctb, lang, qb);
    conv_kernel<<<LPAD2 / 64, 256, 0, stream>>>(lm, kvg, latT);

    int chunk = 0;
    for (int cs = 0; cs < panels_total; cs += ppc, ++chunk) {
        const int np = (panels_total - cs < ppc) ? (panels_total - cs) : ppc;
        gemm1_kernel<<<32 * np, 512, 0, stream>>>(qb, kvg, P, rowsum,
                                                  cs * 128, np, pstride);
        gemm2_kernel<<<32 * 4 * splitk, 512, 0, stream>>>(P, latT, out, parts,
                                                          pstride, np * 128, cs * 128,
                                                          splitk, chunk > 0 ? 1 : 0);
    }
    final_kernel<<<BT / 2, 256, 0, stream>>>(out, parts, lang, rowsum, x, ct, splitk);
}